// Round 2
// baseline (207.998 us; speedup 1.0000x reference)
//
#include <hip/hip_runtime.h>

#define NUM_USERS 100000
#define H1 256
#define H2 128
#define H3 64
#define BATCH 1024

// One WAVE per batch row (256 blocks x 4 waves = 1024 rows).
// The hidden activations are tiny (256/128/64 floats), so they live entirely
// in the owning wave's registers:
//   h1: lane l holds h1[4l..4l+3]   (4 VGPRs)
//   h2: lane l holds h2[2l], h2[2l+1]
//   h3: lane l holds h3[l]
// Per-k broadcasts use v_readlane (VALU, compile-time lane after full unroll)
// instead of LDS: zero __shared__, zero __syncthreads, waves fully decoupled.
// All global loads are coalesced (float4/float2/float per lane); all lanes
// are active at every readlane; only the final store diverges (lane 0).
__device__ __forceinline__ float lane_bcast(float v, int lane) {
    return __uint_as_float(__builtin_amdgcn_readlane(__float_as_uint(v), lane));
}

__global__ __launch_bounds__(256) void mlp_row(
    const int* __restrict__ user_ids,
    const int* __restrict__ item_ids,
    const float* __restrict__ W1, const float* __restrict__ b1,
    const float* __restrict__ W2, const float* __restrict__ b2,
    const float* __restrict__ W3, const float* __restrict__ b3,
    const float* __restrict__ W4, const float* __restrict__ b4,
    float* __restrict__ out)
{
    const int t    = threadIdx.x;
    const int wave = t >> 6;         // 0..3
    const int lane = t & 63;
    const int row  = blockIdx.x * 4 + wave;

    const int u  = user_ids[row];    // wave-uniform load (HW broadcast)
    const int it = item_ids[row];

    // ---- Layer 1: h1 in registers. lane l -> elements 4l..4l+3.
    float hk[4];
    {
        const float4 wu = ((const float4*)(W1 + (size_t)u * H1))[lane];
        const float4 wi = ((const float4*)(W1 + (size_t)(NUM_USERS + it) * H1))[lane];
        const float4 bb = ((const float4*)b1)[lane];
        const float v0 = wu.x + wi.x + bb.x;
        const float v1 = wu.y + wi.y + bb.y;
        const float v2 = wu.z + wi.z + bb.z;
        const float v3 = wu.w + wi.w + bb.w;
        hk[0] = v0 > 0.f ? v0 : 0.f;
        hk[1] = v1 > 0.f ? v1 : 0.f;
        hk[2] = v2 > 0.f ? v2 : 0.f;
        hk[3] = v3 > 0.f ? v3 : 0.f;
    }

    // ---- Layer 2: lane l owns columns {2l, 2l+1}. K=256 fully unrolled,
    //      4-way split accumulators (chain depth 64). h1[k] = reg (k&3) of
    //      lane (k>>2), fetched via readlane with literal lane index.
    float2 acc[4] = {{0.f,0.f},{0.f,0.f},{0.f,0.f},{0.f,0.f}};
    {
        const float2* __restrict__ W2v = (const float2*)W2;  // [256][64] float2
        #pragma unroll
        for (int k = 0; k < H1; ++k) {
            const float  hs = lane_bcast(hk[k & 3], k >> 2);
            const float2 w  = W2v[(size_t)k * (H2 / 2) + lane];
            acc[k & 3].x = fmaf(hs, w.x, acc[k & 3].x);
            acc[k & 3].y = fmaf(hs, w.y, acc[k & 3].y);
        }
    }
    float h2a, h2b;
    {
        const float2 bv = ((const float2*)b2)[lane];
        const float sa = ((acc[0].x + acc[1].x) + (acc[2].x + acc[3].x)) + bv.x;
        const float sb = ((acc[0].y + acc[1].y) + (acc[2].y + acc[3].y)) + bv.y;
        h2a = sa > 0.f ? sa : 0.f;   // h2[2l]
        h2b = sb > 0.f ? sb : 0.f;   // h2[2l+1]
    }

    // ---- Layer 3: lane l owns column l. K=128 fully unrolled, 4-way split.
    //      h2[k] = (k&1 ? h2b : h2a) of lane (k>>1).
    float c0 = 0.f, c1 = 0.f, c2 = 0.f, c3 = 0.f;
    {
        #pragma unroll
        for (int k = 0; k < H2; k += 4) {
            const float s0 = lane_bcast(h2a, (k    ) >> 1);
            const float s1 = lane_bcast(h2b, (k + 1) >> 1);
            const float s2 = lane_bcast(h2a, (k + 2) >> 1);
            const float s3 = lane_bcast(h2b, (k + 3) >> 1);
            c0 = fmaf(s0, W3[(size_t)(k    ) * H3 + lane], c0);
            c1 = fmaf(s1, W3[(size_t)(k + 1) * H3 + lane], c1);
            c2 = fmaf(s2, W3[(size_t)(k + 2) * H3 + lane], c2);
            c3 = fmaf(s3, W3[(size_t)(k + 3) * H3 + lane], c3);
        }
    }
    const float s3s = ((c0 + c1) + (c2 + c3)) + b3[lane];
    const float h3v = s3s > 0.f ? s3s : 0.f;

    // ---- Layer 4: 6-step shuffle-xor tree across the wave.
    float pv = h3v * W4[lane];
    #pragma unroll
    for (int off = 32; off > 0; off >>= 1)
        pv += __shfl_xor(pv, off, 64);
    if (lane == 0)
        out[row] = pv + b4[0];
}

extern "C" void kernel_launch(void* const* d_in, const int* in_sizes, int n_in,
                              void* d_out, int out_size, void* d_ws, size_t ws_size,
                              hipStream_t stream) {
    const int*   user_ids = (const int*)d_in[0];
    const int*   item_ids = (const int*)d_in[1];
    const float* W1 = (const float*)d_in[2];
    const float* b1 = (const float*)d_in[3];
    const float* W2 = (const float*)d_in[4];
    const float* b2 = (const float*)d_in[5];
    const float* W3 = (const float*)d_in[6];
    const float* b3 = (const float*)d_in[7];
    const float* W4 = (const float*)d_in[8];
    const float* b4 = (const float*)d_in[9];
    float* out = (float*)d_out;

    dim3 grid(BATCH / 4);   // one wave per row, 4 rows per block
    dim3 block(256);
    mlp_row<<<grid, block, 0, stream>>>(user_ids, item_ids,
                                        W1, b1, W2, b2, W3, b3, W4, b4, out);
}

// Round 3
// 207.068 us; speedup vs baseline: 1.0045x; 1.0045x over previous
//
#include <hip/hip_runtime.h>

#define NUM_USERS 100000
#define H1 256
#define H2 128
#define H3 64
#define BATCH 1024

// FOUR rows per block (256 blocks x 256 threads = 1 block/CU).
// Key change vs R1/R2: the shared operands (W2, W3) are read ONCE per block
// and amortized over 4 rows, cutting per-CU vector-memory traffic 4x.
// Activations live in LDS TRANSPOSED: h1T[k] = float4{row0..row3}, so the
// L2/L3 inner loop is: 1 b128 LDS broadcast + 1 weight dword + 4 FMAs.
// All LDS reads are wave-uniform broadcasts or lane-contiguous b128;
// the only conflicted access is the tiny h1 transpose-write (16 instrs,
// 8-way). Latency at 1 wave/SIMD is hidden by ILP: fully unrolled loops
// with 8 independent accumulators per thread.
__global__ __launch_bounds__(256) void mlp_row4(
    const int* __restrict__ user_ids,
    const int* __restrict__ item_ids,
    const float* __restrict__ W1, const float* __restrict__ b1,
    const float* __restrict__ W2, const float* __restrict__ b2,
    const float* __restrict__ W3, const float* __restrict__ b3,
    const float* __restrict__ W4, const float* __restrict__ b4,
    float* __restrict__ out)
{
    __shared__ __align__(16) float h1T[H1][4];     // 4 KB  [k][row]
    __shared__ __align__(16) float p2[H2][4];      // 2 KB  upper-K-half partials
    __shared__ __align__(16) float h2T[H2][4];     // 2 KB  [k][row]
    __shared__ __align__(16) float p3[3][H3][4];   // 3 KB  K-quarter partials 1..3

    const int t    = threadIdx.x;
    const int wave = t >> 6;          // 0..3
    const int lane = t & 63;
    const int row0 = blockIdx.x << 2; // rows row0..row0+3

    // ---- Layer 1: wave w computes row w; write transposed into LDS.
    //      lane l handles k = l, l+64, l+128, l+192 (coalesced 256B loads;
    //      ds_write bank = (4l + w) % 32 -> 8-way, only 4 instrs/wave).
    {
        const int u  = user_ids[row0 + wave];   // wave-uniform
        const int it = item_ids[row0 + wave];
        const float* __restrict__ ru = W1 + (size_t)u * H1;
        const float* __restrict__ ri = W1 + (size_t)(NUM_USERS + it) * H1;
        #pragma unroll
        for (int i = 0; i < 4; ++i) {
            const int k = lane + (i << 6);
            const float v = ru[k] + ri[k] + b1[k];
            h1T[k][wave] = v > 0.f ? v : 0.f;
        }
    }
    __syncthreads();

    // ---- Layer 2: thread t -> column j = t&127, K-half kh = t>>7.
    //      Per k: 1 b128 broadcast (4 rows) + 1 W2 dword + 4 FMAs.
    const int j2 = t & (H2 - 1);
    const int kh = t >> 7;                      // 0 or 1
    float a[4][2] = {};                          // [row][k-parity], 8 indep chains
    {
        const float* __restrict__ w2c = W2 + j2; // column j2, stride H2
        const int kbase = kh << 7;
        #pragma unroll
        for (int kk = 0; kk < 128; kk += 2) {
            const float4 hA = *(const float4*)&h1T[kbase + kk    ][0];
            const float4 hB = *(const float4*)&h1T[kbase + kk + 1][0];
            const float wA = w2c[(size_t)(kbase + kk    ) * H2];
            const float wB = w2c[(size_t)(kbase + kk + 1) * H2];
            a[0][0] = fmaf(hA.x, wA, a[0][0]);  a[0][1] = fmaf(hB.x, wB, a[0][1]);
            a[1][0] = fmaf(hA.y, wA, a[1][0]);  a[1][1] = fmaf(hB.y, wB, a[1][1]);
            a[2][0] = fmaf(hA.z, wA, a[2][0]);  a[2][1] = fmaf(hB.z, wB, a[2][1]);
            a[3][0] = fmaf(hA.w, wA, a[3][0]);  a[3][1] = fmaf(hB.w, wB, a[3][1]);
        }
    }
    if (kh == 1) {   // upper half publishes partials (b128, lane-contiguous)
        float4 pp;
        pp.x = a[0][0] + a[0][1];
        pp.y = a[1][0] + a[1][1];
        pp.z = a[2][0] + a[2][1];
        pp.w = a[3][0] + a[3][1];
        *(float4*)&p2[j2][0] = pp;
    }
    __syncthreads();
    if (kh == 0) {   // lower half combines + bias + relu -> h2T (b128 write)
        const float bb = b2[j2];
        float4 hh;
        {
            const float s0 = (a[0][0] + a[0][1]) + p2[j2][0] + bb;
            const float s1 = (a[1][0] + a[1][1]) + p2[j2][1] + bb;
            const float s2 = (a[2][0] + a[2][1]) + p2[j2][2] + bb;
            const float s3 = (a[3][0] + a[3][1]) + p2[j2][3] + bb;
            hh.x = s0 > 0.f ? s0 : 0.f;
            hh.y = s1 > 0.f ? s1 : 0.f;
            hh.z = s2 > 0.f ? s2 : 0.f;
            hh.w = s3 > 0.f ? s3 : 0.f;
        }
        *(float4*)&h2T[j2][0] = hh;
    }
    __syncthreads();

    // ---- Layer 3: thread t -> column j = t&63, K-quarter kq = t>>6.
    const int j3 = t & (H3 - 1);
    const int kq = t >> 6;                      // 0..3 (== wave)
    float c[4][2] = {};
    {
        const float* __restrict__ w3c = W3 + j3;
        const int kbase = kq << 5;
        #pragma unroll
        for (int kk = 0; kk < 32; kk += 2) {
            const float4 hA = *(const float4*)&h2T[kbase + kk    ][0];
            const float4 hB = *(const float4*)&h2T[kbase + kk + 1][0];
            const float wA = w3c[(size_t)(kbase + kk    ) * H3];
            const float wB = w3c[(size_t)(kbase + kk + 1) * H3];
            c[0][0] = fmaf(hA.x, wA, c[0][0]);  c[0][1] = fmaf(hB.x, wB, c[0][1]);
            c[1][0] = fmaf(hA.y, wA, c[1][0]);  c[1][1] = fmaf(hB.y, wB, c[1][1]);
            c[2][0] = fmaf(hA.z, wA, c[2][0]);  c[2][1] = fmaf(hB.z, wB, c[2][1]);
            c[3][0] = fmaf(hA.w, wA, c[3][0]);  c[3][1] = fmaf(hB.w, wB, c[3][1]);
        }
    }
    if (kq != 0) {   // quarters 1..3 publish partials (b128 writes)
        float4 pp;
        pp.x = c[0][0] + c[0][1];
        pp.y = c[1][0] + c[1][1];
        pp.z = c[2][0] + c[2][1];
        pp.w = c[3][0] + c[3][1];
        *(float4*)&p3[kq - 1][j3][0] = pp;
    }
    __syncthreads();

    // ---- L3 combine + Layer 4, wave 0 only (kq==0 holds quarter-0 partials).
    if (t < H3) {
        const float bb = b3[t];
        float h3r[4];
        #pragma unroll
        for (int r = 0; r < 4; ++r) {
            const float s = ((c[r][0] + c[r][1]) + p3[0][t][r])
                          + (p3[1][t][r] + p3[2][t][r]) + bb;
            h3r[r] = s > 0.f ? s : 0.f;
        }
        const float w4 = W4[t];
        float pv0 = h3r[0] * w4, pv1 = h3r[1] * w4;
        float pv2 = h3r[2] * w4, pv3 = h3r[3] * w4;
        #pragma unroll
        for (int off = 32; off > 0; off >>= 1) {
            pv0 += __shfl_xor(pv0, off, 64);
            pv1 += __shfl_xor(pv1, off, 64);
            pv2 += __shfl_xor(pv2, off, 64);
            pv3 += __shfl_xor(pv3, off, 64);
        }
        if (t == 0) {
            const float bo = b4[0];
            float4 o;
            o.x = pv0 + bo;  o.y = pv1 + bo;
            o.z = pv2 + bo;  o.w = pv3 + bo;
            *(float4*)(out + row0) = o;   // rows are contiguous, 16B-aligned
        }
    }
}

extern "C" void kernel_launch(void* const* d_in, const int* in_sizes, int n_in,
                              void* d_out, int out_size, void* d_ws, size_t ws_size,
                              hipStream_t stream) {
    const int*   user_ids = (const int*)d_in[0];
    const int*   item_ids = (const int*)d_in[1];
    const float* W1 = (const float*)d_in[2];
    const float* b1 = (const float*)d_in[3];
    const float* W2 = (const float*)d_in[4];
    const float* b2 = (const float*)d_in[5];
    const float* W3 = (const float*)d_in[6];
    const float* b3 = (const float*)d_in[7];
    const float* W4 = (const float*)d_in[8];
    const float* b4 = (const float*)d_in[9];
    float* out = (float*)d_out;

    dim3 grid(BATCH / 4);   // 4 rows per block, 1 block per CU
    dim3 block(256);
    mlp_row4<<<grid, block, 0, stream>>>(user_ids, item_ids,
                                         W1, b1, W2, b2, W3, b3, W4, b4, out);
}

// Round 4
// 206.086 us; speedup vs baseline: 1.0093x; 1.0048x over previous
//
#include <hip/hip_runtime.h>

#define NUM_USERS 100000
#define H1 256
#define H2 128
#define H3 64
#define BATCH 1024

// R1 structure (1024 blocks x 256 threads, 4 blocks/CU) with the vector-memory
// issue cost attacked: every weight load is a dwordx4 (thread owns a 4-column
// quad), cutting W2/W3 wave-instructions 4x (512+128 -> 128+32 per block).
// K-split partials combine via in-wave shfl_xor butterflies (no p2/p3 LDS
// round-trips; barriers 4 -> 3). h1/h2 stored with +4-float-per-group swizzle
// so the multicast b128 activation reads are bank-conflict-free.
//   L2: thread = (quad q2 = wv*8+(l&7) -> cols 4q2..4q2+3, eighth ke = l>>3)
//   L3: thread = (quad q3 = wv*4+(l&3) -> cols 4q3..4q3+3, 16th  kg = l>>2)
__device__ __forceinline__ float relu_(float x) { return x > 0.f ? x : 0.f; }

__device__ __forceinline__ float4 sxor4(const float4 v, const int off) {
    float4 r;
    r.x = __shfl_xor(v.x, off, 64);
    r.y = __shfl_xor(v.y, off, 64);
    r.z = __shfl_xor(v.z, off, 64);
    r.w = __shfl_xor(v.w, off, 64);
    return r;
}

__global__ __launch_bounds__(256, 4) void mlp_row(
    const int* __restrict__ user_ids,
    const int* __restrict__ item_ids,
    const float* __restrict__ W1, const float* __restrict__ b1,
    const float* __restrict__ W2, const float* __restrict__ b2,
    const float* __restrict__ W3, const float* __restrict__ b3,
    const float* __restrict__ W4, const float* __restrict__ b4,
    float* __restrict__ out)
{
    // swizzled activations: h1s[k + (k>>5)*4], h2s[c + (c>>3)*4]
    __shared__ __align__(16) float h1s[H1 + (H1 / 32) * 4];   // 288 floats
    __shared__ __align__(16) float h2s[H2 + (H2 / 8) * 4];    // 192 floats
    __shared__ float wpart[4];

    const int t   = threadIdx.x;
    const int wv  = t >> 6;        // wave 0..3
    const int l   = t & 63;
    const int row = blockIdx.x;

    const int q2 = (wv << 3) | (l & 7);   // 0..31  (cols 4q2..4q2+3)
    const int ke = l >> 3;                // 0..7   (k in [32ke, 32ke+32))
    const int q3 = (wv << 2) | (l & 3);   // 0..15  (cols 4q3..4q3+3)
    const int kg = l >> 2;                // 0..15  (k in [8kg, 8kg+8))

    // Early independent loads: overlap their latency with the id->W1 chain.
    const float4 b2q = ((const float4*)b2)[q2];
    const float4 b3q = ((const float4*)b3)[q3];
    const float4 w4q = ((const float4*)W4)[q3];
    const float  b4s = b4[0];

    const int u  = user_ids[row];   // wave-uniform -> scalar loads
    const int it = item_ids[row];

    // ---- Layer 1: 1 float per thread, swizzled LDS write (2 lanes/bank).
    {
        const float v = W1[(size_t)u * H1 + t]
                      + W1[(size_t)(NUM_USERS + it) * H1 + t]
                      + b1[t];
        h1s[t + ((t >> 5) << 2)] = relu_(v);
    }
    __syncthreads();

    // ---- Layer 2: 32 k's per thread, dwordx4 weight loads, 2 f4 accumulators.
    float4 a0 = {0.f, 0.f, 0.f, 0.f}, a1 = {0.f, 0.f, 0.f, 0.f};
    {
        const float4* __restrict__ h1q = (const float4*)(h1s + ke * 36);
        const float*  __restrict__ w2b = W2 + (size_t)(ke << 5) * H2 + (q2 << 2);
        #pragma unroll
        for (int i4 = 0; i4 < 8; ++i4) {
            const float4 h  = h1q[i4];   // h1[32ke+4*i4 .. +3], conflict-free multicast
            const float4 wa = *(const float4*)(w2b + (size_t)(4 * i4    ) * H2);
            const float4 wb = *(const float4*)(w2b + (size_t)(4 * i4 + 1) * H2);
            const float4 wc = *(const float4*)(w2b + (size_t)(4 * i4 + 2) * H2);
            const float4 wd = *(const float4*)(w2b + (size_t)(4 * i4 + 3) * H2);
            a0.x = fmaf(h.x, wa.x, a0.x); a0.y = fmaf(h.x, wa.y, a0.y);
            a0.z = fmaf(h.x, wa.z, a0.z); a0.w = fmaf(h.x, wa.w, a0.w);
            a1.x = fmaf(h.y, wb.x, a1.x); a1.y = fmaf(h.y, wb.y, a1.y);
            a1.z = fmaf(h.y, wb.z, a1.z); a1.w = fmaf(h.y, wb.w, a1.w);
            a0.x = fmaf(h.z, wc.x, a0.x); a0.y = fmaf(h.z, wc.y, a0.y);
            a0.z = fmaf(h.z, wc.z, a0.z); a0.w = fmaf(h.z, wc.w, a0.w);
            a1.x = fmaf(h.w, wd.x, a1.x); a1.y = fmaf(h.w, wd.y, a1.y);
            a1.z = fmaf(h.w, wd.z, a1.z); a1.w = fmaf(h.w, wd.w, a1.w);
        }
    }
    float4 s2;
    s2.x = a0.x + a1.x; s2.y = a0.y + a1.y;
    s2.z = a0.z + a1.z; s2.w = a0.w + a1.w;
    {   // butterfly over the 8 ke-groups (lane bits 3..5)
        float4 r;
        r = sxor4(s2,  8); s2.x += r.x; s2.y += r.y; s2.z += r.z; s2.w += r.w;
        r = sxor4(s2, 16); s2.x += r.x; s2.y += r.y; s2.z += r.z; s2.w += r.w;
        r = sxor4(s2, 32); s2.x += r.x; s2.y += r.y; s2.z += r.z; s2.w += r.w;
    }
    if (ke == 0) {   // 8 lanes/wave publish their column-quad (swizzled b128)
        float4 hh;
        hh.x = relu_(s2.x + b2q.x);
        hh.y = relu_(s2.y + b2q.y);
        hh.z = relu_(s2.z + b2q.z);
        hh.w = relu_(s2.w + b2q.w);
        const int c0 = q2 << 2;
        *(float4*)&h2s[c0 + ((c0 >> 3) << 2)] = hh;
    }
    __syncthreads();

    // ---- Layer 3: 8 k's per thread, dwordx4 weight loads.
    float4 c0a = {0.f, 0.f, 0.f, 0.f}, c1a = {0.f, 0.f, 0.f, 0.f};
    {
        const float4* __restrict__ h2q = (const float4*)(h2s + kg * 12);
        const float*  __restrict__ w3b = W3 + (size_t)(kg << 3) * H3 + (q3 << 2);
        const float4 hA = h2q[0];   // h2[8kg   .. +3]
        const float4 hB = h2q[1];   // h2[8kg+4 .. +3]
        const float4 wq0 = *(const float4*)(w3b            );
        const float4 wq1 = *(const float4*)(w3b +     H3   );
        const float4 wq2 = *(const float4*)(w3b + 2 * H3   );
        const float4 wq3 = *(const float4*)(w3b + 3 * H3   );
        const float4 wq4 = *(const float4*)(w3b + 4 * H3   );
        const float4 wq5 = *(const float4*)(w3b + 5 * H3   );
        const float4 wq6 = *(const float4*)(w3b + 6 * H3   );
        const float4 wq7 = *(const float4*)(w3b + 7 * H3   );
        c0a.x = fmaf(hA.x, wq0.x, c0a.x); c0a.y = fmaf(hA.x, wq0.y, c0a.y);
        c0a.z = fmaf(hA.x, wq0.z, c0a.z); c0a.w = fmaf(hA.x, wq0.w, c0a.w);
        c1a.x = fmaf(hA.y, wq1.x, c1a.x); c1a.y = fmaf(hA.y, wq1.y, c1a.y);
        c1a.z = fmaf(hA.y, wq1.z, c1a.z); c1a.w = fmaf(hA.y, wq1.w, c1a.w);
        c0a.x = fmaf(hA.z, wq2.x, c0a.x); c0a.y = fmaf(hA.z, wq2.y, c0a.y);
        c0a.z = fmaf(hA.z, wq2.z, c0a.z); c0a.w = fmaf(hA.z, wq2.w, c0a.w);
        c1a.x = fmaf(hA.w, wq3.x, c1a.x); c1a.y = fmaf(hA.w, wq3.y, c1a.y);
        c1a.z = fmaf(hA.w, wq3.z, c1a.z); c1a.w = fmaf(hA.w, wq3.w, c1a.w);
        c0a.x = fmaf(hB.x, wq4.x, c0a.x); c0a.y = fmaf(hB.x, wq4.y, c0a.y);
        c0a.z = fmaf(hB.x, wq4.z, c0a.z); c0a.w = fmaf(hB.x, wq4.w, c0a.w);
        c1a.x = fmaf(hB.y, wq5.x, c1a.x); c1a.y = fmaf(hB.y, wq5.y, c1a.y);
        c1a.z = fmaf(hB.y, wq5.z, c1a.z); c1a.w = fmaf(hB.y, wq5.w, c1a.w);
        c0a.x = fmaf(hB.z, wq6.x, c0a.x); c0a.y = fmaf(hB.z, wq6.y, c0a.y);
        c0a.z = fmaf(hB.z, wq6.z, c0a.z); c0a.w = fmaf(hB.z, wq6.w, c0a.w);
        c1a.x = fmaf(hB.w, wq7.x, c1a.x); c1a.y = fmaf(hB.w, wq7.y, c1a.y);
        c1a.z = fmaf(hB.w, wq7.z, c1a.z); c1a.w = fmaf(hB.w, wq7.w, c1a.w);
    }
    float4 s3;
    s3.x = c0a.x + c1a.x; s3.y = c0a.y + c1a.y;
    s3.z = c0a.z + c1a.z; s3.w = c0a.w + c1a.w;
    {   // butterfly over the 16 kg-groups (lane bits 2..5)
        float4 r;
        r = sxor4(s3,  4); s3.x += r.x; s3.y += r.y; s3.z += r.z; s3.w += r.w;
        r = sxor4(s3,  8); s3.x += r.x; s3.y += r.y; s3.z += r.z; s3.w += r.w;
        r = sxor4(s3, 16); s3.x += r.x; s3.y += r.y; s3.z += r.z; s3.w += r.w;
        r = sxor4(s3, 32); s3.x += r.x; s3.y += r.y; s3.z += r.z; s3.w += r.w;
    }
    if (kg == 0) {   // lanes 0..3 of each wave: h3 quad + layer-4 partial dot
        const float h30 = relu_(s3.x + b3q.x);
        const float h31 = relu_(s3.y + b3q.y);
        const float h32 = relu_(s3.z + b3q.z);
        const float h33 = relu_(s3.w + b3q.w);
        float pv = fmaf(h30, w4q.x,
                   fmaf(h31, w4q.y,
                   fmaf(h32, w4q.z, h33 * w4q.w)));
        pv += __shfl_xor(pv, 1, 64);   // sources (lanes 0..3) are all active
        pv += __shfl_xor(pv, 2, 64);
        if (l == 0) wpart[wv] = pv;    // per-wave partial over its 16 cols
    }
    __syncthreads();

    if (t == 0)
        out[row] = ((wpart[0] + wpart[1]) + (wpart[2] + wpart[3])) + b4s;
}

extern "C" void kernel_launch(void* const* d_in, const int* in_sizes, int n_in,
                              void* d_out, int out_size, void* d_ws, size_t ws_size,
                              hipStream_t stream) {
    const int*   user_ids = (const int*)d_in[0];
    const int*   item_ids = (const int*)d_in[1];
    const float* W1 = (const float*)d_in[2];
    const float* b1 = (const float*)d_in[3];
    const float* W2 = (const float*)d_in[4];
    const float* b2 = (const float*)d_in[5];
    const float* W3 = (const float*)d_in[6];
    const float* b3 = (const float*)d_in[7];
    const float* W4 = (const float*)d_in[8];
    const float* b4 = (const float*)d_in[9];
    float* out = (float*)d_out;

    dim3 grid(BATCH);   // one block per row, 4 blocks/CU
    dim3 block(256);
    mlp_row<<<grid, block, 0, stream>>>(user_ids, item_ids,
                                        W1, b1, W2, b2, W3, b3, W4, b4, out);
}